// Round 9
// baseline (562.962 us; speedup 1.0000x reference)
//
#include <hip/hip_runtime.h>
#include <math.h>

// Problem constants
#define HO 512
#define WO 512
#define HI 128
#define WI 128
#define CC 64      // channels
#define BS 2       // batch
#define NPX 64     // pixels per block (one row segment)
#define NT 256     // threads per block

// d_ws layout:
//   [0)              bf16 packed weights: w2p then w3p
//   [XT_BYTE_OFF)    x_t padded transpose: float [130][130][64][2]  (c-major, b innermost)
#define W2P_ELEMS (16 * 2 * 64 * 8)      // [nt=16][ks=2][lane=64][j=8]
#define W3P_ELEMS (36 * 8 * 64 * 8)      // [nt=36][ks=8][lane=64][j=8], nt = tap*4+chtile
#define XT_ELEM_OFF (W2P_ELEMS + W3P_ELEMS)     // in shorts (163840 -> 327680 B, 16B aligned)
#define XT_FLOATS (130 * 130 * 128)             // 2,163,200 floats = 8.65 MB

typedef __attribute__((ext_vector_type(8))) short short8;
typedef __attribute__((ext_vector_type(4))) float float4v;
typedef __attribute__((ext_vector_type(2))) float float2v;

__device__ __forceinline__ unsigned short f2bf(float f) {
    unsigned u = __builtin_bit_cast(unsigned, f);
    unsigned r = (u + 0x7FFFu + ((u >> 16) & 1u)) >> 16;   // RNE
    return (unsigned short)r;
}

// ---------------- k1: pack weights to MFMA-B order + zero x_t ----------------
// B-frag (16x16x32): lane l holds B[n=l&15][k=(l>>4)*8+j], j=0..7
// W3 n-tile nt = tap*4 + chtile: covers W3 rows (chtile*16 + (l&15))*9 + tap
// W3 k-PERMUTATION (R6, correctness-verified): stage-2 is computed
// operand-swapped, so its register output holds, at A-frag slot s = lq*8+j of
// k-chunk ks, the h2 feature ks*32 + f(s), f(s) = ((s&4)<<2)|((s>>3)<<2)|(s&3)
// (bijective on [0,32)). MFMA contracts over k, so packing W3 with the SAME
// permutation makes the swapped stage-2 output directly consumable as the
// stage-3 A operand — no transpose, no LDS round-trip.
__global__ void prepack_zw(const float* __restrict__ W2,
                           const float* __restrict__ W3,
                           unsigned short* __restrict__ wsp,
                           float* __restrict__ xt) {
    const int total = W2P_ELEMS + W3P_ELEMS;
    for (int idx = blockIdx.x * blockDim.x + threadIdx.x; idx < total;
         idx += gridDim.x * blockDim.x) {
        float v;
        if (idx < W2P_ELEMS) {
            int j = idx & 7, lane = (idx >> 3) & 63, rest = idx >> 9;
            int ks = rest & 1, nt = rest >> 1;
            int n = nt * 16 + (lane & 15);
            int k = ks * 32 + (lane >> 4) * 8 + j;
            v = W2[n * 64 + k];                      // W2: [256][64]
        } else {
            int i2 = idx - W2P_ELEMS;
            int j = i2 & 7, lane = (i2 >> 3) & 63, rest = i2 >> 9;
            int ks = rest & 7, nt = rest >> 3;       // nt = tap*4+chtile
            int tap = nt >> 2, ct = nt & 3;
            int row = (ct * 16 + (lane & 15)) * 9 + tap;   // < 576
            int s = ((lane >> 4) << 3) | j;                // A-frag slot in chunk
            int fp = ((s & 4) << 2) | ((s >> 3) << 2) | (s & 3);   // permuted feature
            int k = ks * 32 + fp;
            v = W3[row * 256 + k];                   // W3: [576][256]
        }
        wsp[idx] = f2bf(v);
    }
    // zero x_t (borders stay zero; interior overwritten by prepack_x)
    float4v z = {0.f, 0.f, 0.f, 0.f};
    float4v* xt4 = (float4v*)xt;
    for (int i = blockIdx.x * blockDim.x + threadIdx.x; i < XT_FLOATS / 4;
         i += gridDim.x * blockDim.x)
        xt4[i] = z;
}

// ---------------- k2: x -> x_t[(h+1)][(w+1)][c][b] (interior) ----------------
// 262144 threads; lanes consecutive = consecutive w -> coalesced reads.
// Batch innermost: each stage-3 tap gather is ONE float2 load (R4 win: -18us).
__global__ void prepack_x(const float* __restrict__ x, float* __restrict__ xt) {
    const int tid = blockIdx.x * blockDim.x + threadIdx.x;
    const int pos = tid & 16383;          // h*128+w
    const int g   = tid >> 14;            // channel group: 4 channels x 2 batches
    const int h = pos >> 7, w = pos & 127;
    const float* src = x + pos;
    float a0[4], a1[4];
    #pragma unroll
    for (int j = 0; j < 4; ++j) a0[j] = src[(size_t)(g * 4 + j) * (HI * WI)];            // b=0
    #pragma unroll
    for (int j = 0; j < 4; ++j) a1[j] = src[(size_t)(CC + g * 4 + j) * (HI * WI)];       // b=1
    float* dst = xt + ((h + 1) * 130 + (w + 1)) * 128 + g * 8;
    *(float4v*)dst       = (float4v){a0[0], a1[0], a0[1], a1[1]};
    *(float4v*)(dst + 4) = (float4v){a0[2], a1[2], a0[3], a1[3]};
}

// ---------------- fused main kernel ----------------
// R9 = R8 with the SCRATCH ROOT CAUSE fixed per rule #20's prescription:
// h2f[8] was an alloca living ACROSS the runtime ct loop; SROA runs before
// loop-unroll makes its indices constant, so it stayed in scratch (R7/R8:
// VGPR=84, WRITE 388MB, ~260B/thread spill round-trip). Fix: EIGHT NAMED
// short8 locals (never address-taken -> pure SSA values -> must live in
// VGPRs). Stage-2 assigns them with literal kc; stage-3 consumes them with
// literal ks via macros. Everything else identical to R8.
__global__ __launch_bounds__(NT, 3)
void fused_main(const float* __restrict__ xt, const float* __restrict__ pose,
                const float* __restrict__ W1, const float* __restrict__ b1,
                const float* __restrict__ b2, const float* __restrict__ b3,
                const int* __restrict__ iY, const int* __restrict__ iX,
                const unsigned short* __restrict__ wsp,
                float* __restrict__ out)
{
    // Manual LDS layout (27904 B).
    __shared__ char smem[9216 + 17408 + 768 + 512];
    unsigned short (*sH1)[72]  = (unsigned short (*)[72])&smem[0];         // 9216 B
    float (*sOut)[2][16][68]   = (float (*)[2][16][68])&smem[9216];        // 17408 B
    float (*sP)[NPX]           = (float (*)[NPX])&smem[26624];             // 768 B
    int* sIY                   = (int*)&smem[27392];                       // 256 B
    int* sIX                   = (int*)&smem[27648];                       // 256 B

    const int t = threadIdx.x;
    const int pixBase = blockIdx.x * NPX;    // 64 px within one output row
    const int y  = pixBase / WO;
    const int x0 = pixBase % WO;

    if (t < 192) sP[t >> 6][t & 63] = pose[(t >> 6) * (HO * WO) + pixBase + (t & 63)];
    if (t < 64) sIY[t] = iY[pixBase + t];
    else if (t < 128) sIX[t - 64] = iX[pixBase + t - 64];
    __syncthreads();

    // ---- stage 1: h1 = relu(W1 @ p + b1)  (wave = feature-group)
    {
        const int p  = t & 63;
        const int og = t >> 6;
        const float p0 = sP[0][p], p1 = sP[1][p], p2 = sP[2][p];
        #pragma unroll
        for (int i = 0; i < 16; i += 2) {
            const int o = og * 16 + i;
            float a0 = fmaf(W1[o * 3 + 2], p2, fmaf(W1[o * 3 + 1], p1, fmaf(W1[o * 3 + 0], p0, b1[o])));
            float a1 = fmaf(W1[o * 3 + 5], p2, fmaf(W1[o * 3 + 4], p1, fmaf(W1[o * 3 + 3], p0, b1[o + 1])));
            a0 = fmaxf(a0, 0.f); a1 = fmaxf(a1, 0.f);
            unsigned pack = (unsigned)f2bf(a0) | ((unsigned)f2bf(a1) << 16);
            *(unsigned*)&sH1[p][o] = pack;
        }
    }
    __syncthreads();

    const int wv = t >> 6, l = t & 63, lm = l & 15, lq = l >> 4;
    const int m0 = wv * 16;                  // wave's pixel base

    // ---- stage 2 (ONCE, operand-swapped): h2 for this wave's 16 px,
    //      directly in A-frag layout. 8 NAMED short8 = 32 VGPRs, SSA values.
    short8 h2f0, h2f1, h2f2, h2f3, h2f4, h2f5, h2f6, h2f7;
    {
        // h1 frags (px on lm, h1-feature on lq*8+j) — same layout serves as
        // the B operand of the swapped MFMA.
        short8 a0 = *(const short8*)&sH1[m0 + lm][0  + lq * 8];
        short8 a1 = *(const short8*)&sH1[m0 + lm][32 + lq * 8];
        const short8* w2f = (const short8*)wsp;

#define S2STEP(KC, H)                                                         \
        {                                                                     \
            const int ntE = 2 * (KC), ntO = 2 * (KC) + 1;                     \
            float4v aE = {0.f, 0.f, 0.f, 0.f}, aO = {0.f, 0.f, 0.f, 0.f};     \
            short8 e0 = w2f[(ntE * 2 + 0) * 64 + l];                          \
            short8 e1 = w2f[(ntE * 2 + 1) * 64 + l];                          \
            short8 o0 = w2f[(ntO * 2 + 0) * 64 + l];                          \
            short8 o1 = w2f[(ntO * 2 + 1) * 64 + l];                          \
            aE = __builtin_amdgcn_mfma_f32_16x16x32_bf16(e0, a0, aE, 0, 0, 0);\
            aE = __builtin_amdgcn_mfma_f32_16x16x32_bf16(e1, a1, aE, 0, 0, 0);\
            aO = __builtin_amdgcn_mfma_f32_16x16x32_bf16(o0, a0, aO, 0, 0, 0);\
            aO = __builtin_amdgcn_mfma_f32_16x16x32_bf16(o1, a1, aO, 0, 0, 0);\
            const float4v bE = *(const float4v*)(b2 + ntE * 16 + lq * 4);     \
            const float4v bO = *(const float4v*)(b2 + ntO * 16 + lq * 4);     \
            short8 h;                                                         \
            h[0] = (short)f2bf(fmaxf(aE[0] + bE[0], 0.f));                    \
            h[1] = (short)f2bf(fmaxf(aE[1] + bE[1], 0.f));                    \
            h[2] = (short)f2bf(fmaxf(aE[2] + bE[2], 0.f));                    \
            h[3] = (short)f2bf(fmaxf(aE[3] + bE[3], 0.f));                    \
            h[4] = (short)f2bf(fmaxf(aO[0] + bO[0], 0.f));                    \
            h[5] = (short)f2bf(fmaxf(aO[1] + bO[1], 0.f));                    \
            h[6] = (short)f2bf(fmaxf(aO[2] + bO[2], 0.f));                    \
            h[7] = (short)f2bf(fmaxf(aO[3] + bO[3], 0.f));                    \
            H = h;                                                            \
        }
        S2STEP(0, h2f0)
        S2STEP(1, h2f1)
        S2STEP(2, h2f2)
        S2STEP(3, h2f3)
        S2STEP(4, h2f4)
        S2STEP(5, h2f5)
        S2STEP(6, h2f6)
        S2STEP(7, h2f7)
#undef S2STEP
    }

    // per-lane pixel bases into x_t (pixels p = m0 + lq*4 + r)
    int pbase[4];
    #pragma unroll
    for (int r = 0; r < 4; ++r) {
        const int p = m0 + lq * 4 + r;
        pbase[r] = ((sIY[p] + 1) * 130 + (sIX[p] + 1)) * 128;
    }
    const int koff[9] = {-131 * 128, -130 * 128, -129 * 128,
                         -1 * 128,   0,          1 * 128,
                         129 * 128,  130 * 128,  131 * 128};
    const short8* w3f = (const short8*)(wsp + W2P_ELEMS);

    // ---- stage 3: 4 chtiles of 16 channels; h2 A-frags straight from
    //      named registers (literal ks via macro).
    for (int ct = 0; ct < 4; ++ct) {
        float4v accs[9];
        #pragma unroll
        for (int tap = 0; tap < 9; ++tap) accs[tap] = (float4v){0.f, 0.f, 0.f, 0.f};

#define KSTEP(KS, H)                                                          \
        {                                                                     \
            _Pragma("unroll")                                                 \
            for (int tap = 0; tap < 9; ++tap) {                               \
                short8 b = w3f[(((tap << 2) | ct) * 8 + (KS)) * 64 + l];      \
                accs[tap] = __builtin_amdgcn_mfma_f32_16x16x32_bf16(          \
                    H, b, accs[tap], 0, 0, 0);                                \
            }                                                                 \
        }
        KSTEP(0, h2f0)
        KSTEP(1, h2f1)
        KSTEP(2, h2f2)
        KSTEP(3, h2f3)
        KSTEP(4, h2f4)
        KSTEP(5, h2f5)
        KSTEP(6, h2f6)
        KSTEP(7, h2f7)
#undef KSTEP

        const int c = ct * 16 + lm;          // this lane's channel
        float bv[9];
        #pragma unroll
        for (int tap = 0; tap < 9; ++tap) bv[tap] = b3[c * 9 + tap];

        float ob0[4], ob1[4];
        #pragma unroll
        for (int r = 0; r < 4; ++r) {
            float lg[9];
            #pragma unroll
            for (int tap = 0; tap < 9; ++tap) lg[tap] = accs[tap][r] + bv[tap];
            float mx = lg[0];
            #pragma unroll
            for (int tap = 1; tap < 9; ++tap) mx = fmaxf(mx, lg[tap]);
            const float* xb = xt + pbase[r] + 2 * c;
            float s = 0.f, o0 = 0.f, o1 = 0.f;
            #pragma unroll
            for (int tap = 0; tap < 9; ++tap) {
                const float ev = __expf(lg[tap] - mx);
                const float2v gg = *(const float2v*)(xb + koff[tap]);  // one 8B load: b=0,b=1
                s += ev;
                o0 = fmaf(ev, gg[0], o0);
                o1 = fmaf(ev, gg[1], o1);
            }
            const float inv = 1.f / s;
            ob0[r] = o0 * inv;
            ob1[r] = o1 * inv;
        }

        // transpose via LDS (double-buffered) -> coalesced full-line stores
        float (*so)[16][68] = sOut[ct & 1];
        *(float4v*)&so[0][lm][m0 + lq * 4] = (float4v){ob0[0], ob0[1], ob0[2], ob0[3]};
        *(float4v*)&so[1][lm][m0 + lq * 4] = (float4v){ob1[0], ob1[1], ob1[2], ob1[3]};
        __syncthreads();   // cross-lane handoff (R2 lesson: never skip)

        const int row = t >> 3;              // 0..31 = (b,ch16)
        const int b   = row >> 4, ch = row & 15;
        const int seg = (t & 7) * 8;
        float4v v0 = *(float4v*)&so[b][ch][seg];
        float4v v1 = *(float4v*)&so[b][ch][seg + 4];
        float* op = out + (((size_t)(b * CC + ct * 16 + ch) * HO) + y) * WO + x0 + seg;
        *(float4v*)op = v0;
        *(float4v*)(op + 4) = v1;
        // next ct writes the other sOut buffer; the barrier inside ct+1
        // orders ct's reads before ct+2's writes
    }
}

extern "C" void kernel_launch(void* const* d_in, const int* in_sizes, int n_in,
                              void* d_out, int out_size, void* d_ws, size_t ws_size,
                              hipStream_t stream) {
    const float* x    = (const float*)d_in[0];
    const float* pose = (const float*)d_in[1];
    const float* W1   = (const float*)d_in[2];
    const float* b1   = (const float*)d_in[3];
    const float* W2   = (const float*)d_in[4];
    const float* b2   = (const float*)d_in[5];
    const float* W3   = (const float*)d_in[6];
    const float* b3   = (const float*)d_in[7];
    const int*   iY   = (const int*)d_in[8];
    const int*   iX   = (const int*)d_in[9];
    float* out = (float*)d_out;
    unsigned short* wsp = (unsigned short*)d_ws;
    float* xt = (float*)((char*)d_ws + XT_ELEM_OFF * sizeof(unsigned short));

    prepack_zw<<<2048, NT, 0, stream>>>(W2, W3, wsp, xt);
    prepack_x<<<1024, NT, 0, stream>>>(x, xt);

    const int nblocks = (HO * WO) / NPX;   // 4096
    fused_main<<<nblocks, NT, 0, stream>>>(
        xt, pose, W1, b1, b2, b3, iY, iX, wsp, out);
}

// Round 10
// 399.524 us; speedup vs baseline: 1.4091x; 1.4091x over previous
//
#include <hip/hip_runtime.h>
#include <math.h>

// Problem constants
#define HO 512
#define WO 512
#define HI 128
#define WI 128
#define CC 64      // channels
#define BS 2       // batch
#define NPX 64     // pixels per block (one row segment)
#define NT 256     // threads per block

// d_ws layout:
//   [0)              bf16 packed weights: w2p then w3p
//   [XT_BYTE_OFF)    x_t padded transpose: float [130][130][64][2]  (c-major, b innermost)
#define W2P_ELEMS (16 * 2 * 64 * 8)      // [nt=16][ks=2][lane=64][j=8]  = 16384
#define W3P_ELEMS (36 * 8 * 64 * 8)      // [nt=36][ks=8][lane=64][j=8]  = 147456
#define TOTALW    (W2P_ELEMS + W3P_ELEMS)       // 163840
#define XT_ELEM_OFF TOTALW                      // in shorts (327680 B, 16B aligned)
#define NBORDER4  16512                          // border float4s: 2*130*32 + 128*2*32

typedef __attribute__((ext_vector_type(8))) short short8;
typedef __attribute__((ext_vector_type(4))) short short4v;
typedef __attribute__((ext_vector_type(4))) float float4v;
typedef __attribute__((ext_vector_type(2))) float float2v;

__device__ __forceinline__ unsigned short f2bf(float f) {
    unsigned u = __builtin_bit_cast(unsigned, f);
    unsigned r = (u + 0x7FFFu + ((u >> 16) & 1u)) >> 16;   // RNE
    return (unsigned short)r;
}

// ---------------- single prepack kernel ----------------
// tid [0, 262144): x -> x_t[(h+1)][(w+1)][c][b] interior transpose (R4 path)
// tid [262144, 524288): weights bf16 pack (NATURAL W3 k-order, R4's) +
//                       border-only x_t zero (the gathers touch only a
//                       1-cell halo; zeroing 264KB instead of 8.65MB).
// All ranges disjoint -> no ordering hazard; one launch instead of two.
__global__ void prepack_all(const float* __restrict__ x,
                            const float* __restrict__ W2,
                            const float* __restrict__ W3,
                            unsigned short* __restrict__ wsp,
                            float* __restrict__ xt) {
    const int tid = blockIdx.x * blockDim.x + threadIdx.x;   // 2048*256
    if (tid < 262144) {
        const int pos = tid & 16383;          // h*128+w
        const int g   = tid >> 14;            // channel group: 4 ch x 2 batches
        const int h = pos >> 7, w = pos & 127;
        const float* src = x + pos;
        float a0[4], a1[4];
        #pragma unroll
        for (int j = 0; j < 4; ++j) a0[j] = src[(size_t)(g * 4 + j) * (HI * WI)];        // b=0
        #pragma unroll
        for (int j = 0; j < 4; ++j) a1[j] = src[(size_t)(CC + g * 4 + j) * (HI * WI)];   // b=1
        float* dst = xt + ((h + 1) * 130 + (w + 1)) * 128 + g * 8;
        *(float4v*)dst       = (float4v){a0[0], a1[0], a0[1], a1[1]};
        *(float4v*)(dst + 4) = (float4v){a0[2], a1[2], a0[3], a1[3]};
        return;
    }
    const int idx = tid - 262144;             // 262144 aux slots, single pass
    if (idx < W2P_ELEMS) {
        int j = idx & 7, lane = (idx >> 3) & 63, rest = idx >> 9;
        int ks = rest & 1, nt = rest >> 1;
        int n = nt * 16 + (lane & 15);
        int k = ks * 32 + (lane >> 4) * 8 + j;
        wsp[idx] = f2bf(W2[n * 64 + k]);      // W2: [256][64]
    } else if (idx < TOTALW) {
        int i2 = idx - W2P_ELEMS;
        int j = i2 & 7, lane = (i2 >> 3) & 63, rest = i2 >> 9;
        int ks = rest & 7, nt = rest >> 3;    // nt = tap*4+chtile
        int tap = nt >> 2, ct = nt & 3;
        int row = (ct * 16 + (lane & 15)) * 9 + tap;   // < 576
        int k = ks * 32 + (lane >> 4) * 8 + j;         // NATURAL k-order (R4)
        wsp[idx] = f2bf(W3[row * 256 + k]);   // W3: [576][256]
    } else if (idx < TOTALW + NBORDER4) {
        int a = idx - TOTALW;                 // border float4 index
        int cell;                             // h*130+w of a border cell
        if (a < 2 * 130 * 32) {               // rows h=0 and h=129 (full)
            int r = a / (130 * 32);
            int rest = a - r * (130 * 32);
            cell = (r * 129) * 130 + (rest >> 5);
            a = rest;
        } else {                              // cols w=0 and w=129, h=1..128
            int a2 = a - 2 * 130 * 32;
            int h = 1 + (a2 >> 6);            // 64 float4 per h (2 cells x 32)
            int rest = a2 & 63;
            cell = h * 130 + (rest >> 5) * 129;
            a = rest;
        }
        float4v z = {0.f, 0.f, 0.f, 0.f};
        *(float4v*)(xt + (size_t)cell * 128 + (a & 31) * 4) = z;
    }
}

// ---------------- fused main kernel ----------------
// R10 = R4 (proven 285us: sH2 in LDS, inline float2 gathers, LDS transpose +
// full-line stores) with ONE stage-2 change: operand-swapped MFMA
// (mfma(W2frag, h1frag)) puts px on lm / feature on lq*4+r, so sH2 is
// written DIRECTLY in [px][feature] natural order via 16 ds_write_b64
// instead of R4's 64-scalar ds_write_b16 transpose-scatter (which caused
// ~2.1M of R4's 2.75M LDS bank conflicts). W3 stays NATURAL-packed (the
// swapped D layout needs no k-permutation). h2 never lives in registers
// across stage 3 -> the R6-R9 spill trap is structurally avoided.
__global__ __launch_bounds__(NT, 3)
void fused_main(const float* __restrict__ xt, const float* __restrict__ pose,
                const float* __restrict__ W1, const float* __restrict__ b1,
                const float* __restrict__ b2, const float* __restrict__ b3,
                const int* __restrict__ iY, const int* __restrict__ iX,
                const unsigned short* __restrict__ wsp,
                float* __restrict__ out)
{
    // Manual LDS layout (52.5 KB -> 3 blocks/CU). sH1 dead after stage2;
    // overlap it with the double-buffered sOut transpose tile.
    __shared__ char smem[33792 + 17408 + 768 + 512];
    unsigned short (*sH2)[264] = (unsigned short (*)[264])&smem[0];        // 33792 B
    unsigned short (*sH1)[72]  = (unsigned short (*)[72])&smem[33792];     // 9216 B (union)
    float (*sOut)[2][16][68]   = (float (*)[2][16][68])&smem[33792];       // 2x8704 B (union)
    float (*sP)[NPX]           = (float (*)[NPX])&smem[51200];             // 768 B
    int* sIY                   = (int*)&smem[51968];                       // 256 B
    int* sIX                   = (int*)&smem[52224];                       // 256 B

    const int t = threadIdx.x;
    const int pixBase = blockIdx.x * NPX;    // 64 px within one output row
    const int y  = pixBase / WO;
    const int x0 = pixBase % WO;

    if (t < 192) sP[t >> 6][t & 63] = pose[(t >> 6) * (HO * WO) + pixBase + (t & 63)];
    if (t < 64) sIY[t] = iY[pixBase + t];
    else if (t < 128) sIX[t - 64] = iX[pixBase + t - 64];
    __syncthreads();

    // ---- stage 1: h1 = relu(W1 @ p + b1)
    {
        const int p  = t & 63;
        const int og = t >> 6;
        const float p0 = sP[0][p], p1 = sP[1][p], p2 = sP[2][p];
        #pragma unroll
        for (int i = 0; i < 16; i += 2) {
            const int o = og * 16 + i;
            float a0 = fmaf(W1[o * 3 + 2], p2, fmaf(W1[o * 3 + 1], p1, fmaf(W1[o * 3 + 0], p0, b1[o])));
            float a1 = fmaf(W1[o * 3 + 5], p2, fmaf(W1[o * 3 + 4], p1, fmaf(W1[o * 3 + 3], p0, b1[o + 1])));
            a0 = fmaxf(a0, 0.f); a1 = fmaxf(a1, 0.f);
            unsigned pack = (unsigned)f2bf(a0) | ((unsigned)f2bf(a1) << 16);
            *(unsigned*)&sH1[p][o] = pack;
        }
    }
    __syncthreads();

    const int wv = t >> 6, l = t & 63, lm = l & 15, lq = l >> 4;
    const int m0 = wv * 16;                  // wave's pixel base

    // ---- stage 2 (operand-swapped): h2 = relu(h1 @ W2^T + b2), written to
    //      sH2[px][feature] in natural order via ds_write_b64.
    //      A=W2frag (feature on lm), B=h1frag (px on lm)
    //      -> D: col(lane&15)=px, row(lq*4+r)=feature within the 16-tile.
    {
        short8 a0 = *(const short8*)&sH1[m0 + lm][0  + lq * 8];
        short8 a1 = *(const short8*)&sH1[m0 + lm][32 + lq * 8];
        const short8* w2f = (const short8*)wsp;
        #pragma unroll 4
        for (int kc = 0; kc < 8; ++kc) {
            const int ntE = 2 * kc, ntO = 2 * kc + 1;
            float4v aE = {0.f, 0.f, 0.f, 0.f}, aO = {0.f, 0.f, 0.f, 0.f};
            short8 e0 = w2f[(ntE * 2 + 0) * 64 + l];
            short8 e1 = w2f[(ntE * 2 + 1) * 64 + l];
            short8 o0 = w2f[(ntO * 2 + 0) * 64 + l];
            short8 o1 = w2f[(ntO * 2 + 1) * 64 + l];
            aE = __builtin_amdgcn_mfma_f32_16x16x32_bf16(e0, a0, aE, 0, 0, 0);
            aE = __builtin_amdgcn_mfma_f32_16x16x32_bf16(e1, a1, aE, 0, 0, 0);
            aO = __builtin_amdgcn_mfma_f32_16x16x32_bf16(o0, a0, aO, 0, 0, 0);
            aO = __builtin_amdgcn_mfma_f32_16x16x32_bf16(o1, a1, aO, 0, 0, 0);
            const float4v bE = *(const float4v*)(b2 + ntE * 16 + lq * 4);
            const float4v bO = *(const float4v*)(b2 + ntO * 16 + lq * 4);
            short4v hE, hO;
            #pragma unroll
            for (int r = 0; r < 4; ++r) {
                hE[r] = (short)f2bf(fmaxf(aE[r] + bE[r], 0.f));
                hO[r] = (short)f2bf(fmaxf(aO[r] + bO[r], 0.f));
            }
            // lane (lm,lq) holds features kc*32 + lq*4..+3 (E) / +16.. (O)
            // of pixel m0+lm: two 8B stores, 2-way bank aliasing only (free).
            *(short4v*)&sH2[m0 + lm][kc * 32 + lq * 4]      = hE;
            *(short4v*)&sH2[m0 + lm][kc * 32 + 16 + lq * 4] = hO;
        }
    }
    __syncthreads();   // sH1 also dead beyond this point (sOut may overwrite)

    // per-lane pixel bases into x_t (pixels p = m0 + lq*4 + r)
    int pbase[4];
    #pragma unroll
    for (int r = 0; r < 4; ++r) {
        const int p = m0 + lq * 4 + r;
        pbase[r] = ((sIY[p] + 1) * 130 + (sIX[p] + 1)) * 128;
    }
    const int koff[9] = {-131 * 128, -130 * 128, -129 * 128,
                         -1 * 128,   0,          1 * 128,
                         129 * 128,  130 * 128,  131 * 128};
    const short8* w3f = (const short8*)(wsp + W2P_ELEMS);

    // ---- stage 3: 4 chtiles of 16 channels; 9 taps in registers (R4 code)
    for (int ct = 0; ct < 4; ++ct) {
        float4v accs[9];
        #pragma unroll
        for (int tap = 0; tap < 9; ++tap) accs[tap] = (float4v){0.f, 0.f, 0.f, 0.f};

        #pragma unroll 2
        for (int ks = 0; ks < 8; ++ks) {
            short8 a = *(const short8*)&sH2[m0 + lm][ks * 32 + lq * 8];
            #pragma unroll
            for (int tap = 0; tap < 9; ++tap) {
                short8 b = w3f[(((tap << 2) | ct) * 8 + ks) * 64 + l];
                accs[tap] = __builtin_amdgcn_mfma_f32_16x16x32_bf16(a, b, accs[tap], 0, 0, 0);
            }
        }

        const int c = ct * 16 + lm;          // this lane's channel
        float bv[9];
        #pragma unroll
        for (int tap = 0; tap < 9; ++tap) bv[tap] = b3[c * 9 + tap];

        float ob0[4], ob1[4];
        #pragma unroll
        for (int r = 0; r < 4; ++r) {
            float lg[9];
            #pragma unroll
            for (int tap = 0; tap < 9; ++tap) lg[tap] = accs[tap][r] + bv[tap];
            float mx = lg[0];
            #pragma unroll
            for (int tap = 1; tap < 9; ++tap) mx = fmaxf(mx, lg[tap]);
            const float* xb = xt + pbase[r] + 2 * c;
            float s = 0.f, o0 = 0.f, o1 = 0.f;
            #pragma unroll
            for (int tap = 0; tap < 9; ++tap) {
                const float ev = __expf(lg[tap] - mx);
                const float2v gg = *(const float2v*)(xb + koff[tap]);  // one 8B load: b=0,b=1
                s += ev;
                o0 = fmaf(ev, gg[0], o0);
                o1 = fmaf(ev, gg[1], o1);
            }
            const float inv = 1.f / s;
            ob0[r] = o0 * inv;
            ob1[r] = o1 * inv;
        }

        // transpose via LDS (double-buffered) -> coalesced full-line stores
        float (*so)[16][68] = sOut[ct & 1];
        *(float4v*)&so[0][lm][m0 + lq * 4] = (float4v){ob0[0], ob0[1], ob0[2], ob0[3]};
        *(float4v*)&so[1][lm][m0 + lq * 4] = (float4v){ob1[0], ob1[1], ob1[2], ob1[3]};
        __syncthreads();   // cross-lane handoff (R2 lesson: never skip)

        const int row = t >> 3;              // 0..31 = (b,ch16)
        const int b   = row >> 4, ch = row & 15;
        const int seg = (t & 7) * 8;
        float4v v0 = *(float4v*)&so[b][ch][seg];
        float4v v1 = *(float4v*)&so[b][ch][seg + 4];
        float* op = out + (((size_t)(b * CC + ct * 16 + ch) * HO) + y) * WO + x0 + seg;
        *(float4v*)op = v0;
        *(float4v*)(op + 4) = v1;
        // next ct writes the other sOut buffer -> no WAR barrier needed
    }
}

extern "C" void kernel_launch(void* const* d_in, const int* in_sizes, int n_in,
                              void* d_out, int out_size, void* d_ws, size_t ws_size,
                              hipStream_t stream) {
    const float* x    = (const float*)d_in[0];
    const float* pose = (const float*)d_in[1];
    const float* W1   = (const float*)d_in[2];
    const float* b1   = (const float*)d_in[3];
    const float* W2   = (const float*)d_in[4];
    const float* b2   = (const float*)d_in[5];
    const float* W3   = (const float*)d_in[6];
    const float* b3   = (const float*)d_in[7];
    const int*   iY   = (const int*)d_in[8];
    const int*   iX   = (const int*)d_in[9];
    float* out = (float*)d_out;
    unsigned short* wsp = (unsigned short*)d_ws;
    float* xt = (float*)((char*)d_ws + (size_t)XT_ELEM_OFF * sizeof(unsigned short));

    prepack_all<<<2048, NT, 0, stream>>>(x, W2, W3, wsp, xt);

    const int nblocks = (HO * WO) / NPX;   // 4096
    fused_main<<<nblocks, NT, 0, stream>>>(
        xt, pose, W1, b1, b2, b3, iY, iX, wsp, out);
}